// Round 6
// baseline (297.004 us; speedup 1.0000x reference)
//
#include <hip/hip_runtime.h>
#include <hip/hip_bf16.h>
#include <stdint.h>

// Problem constants (from reference): B=2, L=4096, H=1024
#define BB 2
#define LL 4096
#define HH 1024
#define GBK 32   // fallback GEMM K-tile

typedef __bf16 bf16;
typedef __bf16 bf16x4 __attribute__((ext_vector_type(4)));
typedef __bf16 bf16x8 __attribute__((ext_vector_type(8)));
typedef float  f32x4  __attribute__((ext_vector_type(4)));

// ---------------------------------------------------------------------------
// async global->LDS, 16 B per lane (m104/m108 semantics).
// ---------------------------------------------------------------------------
__device__ __forceinline__ void async_cp16(const bf16* g, const bf16* l)
{
    typedef const uint32_t __attribute__((address_space(1)))* gp_t;
    typedef uint32_t __attribute__((address_space(3)))* lp_t;
    __builtin_amdgcn_global_load_lds((gp_t)(uintptr_t)g, (lp_t)(uintptr_t)l, 16, 0, 0);
}

__device__ __forceinline__ uint32_t pack_bf16(float lo, float hi)
{
    union { bf16 b; unsigned short u; } a, c;
    a.b = (bf16)lo; c.b = (bf16)hi;
    return (uint32_t)a.u | ((uint32_t)c.u << 16);
}

// ---------------------------------------------------------------------------
// FUSED prep kernel: RoPE (fp32 -> bf16 h), transpose (h -> hT), Wq cast,
// and split-K ticket zeroing (tickets consumed by gemm8_Gq's fused reduce;
// stream order guarantees visibility).
// cos/sin dedup: cos[l, i+512] == cos[l, i] (emb = concat([freqs, freqs])).
// ---------------------------------------------------------------------------
__global__ __launch_bounds__(256) void prep_kernel(
    const float* __restrict__ x, const float* __restrict__ cs,
    const float* __restrict__ sn, const float* __restrict__ Wq,
    bf16* __restrict__ h, bf16* __restrict__ hT, bf16* __restrict__ Wb,
    unsigned* __restrict__ tickets)
{
    const int id = blockIdx.x;
    if (id >= 1024) {                      // ---- Wq cast tail: 256 blocks
        if (id == 1024 && threadIdx.x < 32) tickets[threadIdx.x] = 0u;
        const long base = (long)(id - 1024) * 4096 + (long)threadIdx.x * 16;
#pragma unroll
        for (int j = 0; j < 4; ++j) {
            const float4 v = *(const float4*)(Wq + base + j * 4);
            bf16x4 o;
            o[0] = (bf16)v.x; o[1] = (bf16)v.y; o[2] = (bf16)v.z; o[3] = (bf16)v.w;
            *(bf16x4*)(Wb + base + j * 4) = o;
        }
        return;
    }
    __shared__ uint32_t lds[2][64][36];    // [strip][col][row-pair], 18 KiB
    const int b  = id >> 9;
    const int v  = id & 511;
    const int r0 = (v >> 3) * 64;
    const int c0 = (v & 7) * 64;           // strip A cols [c0,c0+64); B = +512
    const int t  = threadIdx.x;
    const int c8 = t & 7;                  // col octet within strip
    const int rr = t >> 3;                 // row pair 0..31
    const int ca = c0 + c8 * 8;
    const long xrow0 = ((long)b * LL + r0 + 2 * rr) * HH;
    const long crow0 = (long)(r0 + 2 * rr) * HH;

    float oA[2][8], oB[2][8];
#pragma unroll
    for (int rw = 0; rw < 2; ++rw) {
        const long xr = xrow0 + (long)rw * HH;
        const long cr = crow0 + (long)rw * HH;
        float xA[8], xB[8], cA[8], sA[8];
        *(float4*)&xA[0] = *(const float4*)(x + xr + ca);
        *(float4*)&xA[4] = *(const float4*)(x + xr + ca + 4);
        *(float4*)&xB[0] = *(const float4*)(x + xr + ca + 512);
        *(float4*)&xB[4] = *(const float4*)(x + xr + ca + 516);
        *(float4*)&cA[0] = *(const float4*)(cs + cr + ca);
        *(float4*)&cA[4] = *(const float4*)(cs + cr + ca + 4);
        *(float4*)&sA[0] = *(const float4*)(sn + cr + ca);
        *(float4*)&sA[4] = *(const float4*)(sn + cr + ca + 4);
#pragma unroll
        for (int j = 0; j < 8; ++j) {
            oA[rw][j] = xA[j] * cA[j] - xB[j] * sA[j];   // first-half out
            oB[rw][j] = xB[j] * cA[j] + xA[j] * sA[j];   // second-half out
        }
        bf16x8 hA, hB;
#pragma unroll
        for (int j = 0; j < 8; ++j) { hA[j] = (bf16)oA[rw][j]; hB[j] = (bf16)oB[rw][j]; }
        *(bf16x8*)(h + xr + ca)       = hA;
        *(bf16x8*)(h + xr + ca + 512) = hB;
    }
#pragma unroll
    for (int j = 0; j < 8; ++j) {
        lds[0][c8 * 8 + j][rr] = pack_bf16(oA[0][j], oA[1][j]);
        lds[1][c8 * 8 + j][rr] = pack_bf16(oB[0][j], oB[1][j]);
    }
    __syncthreads();

    const int cc = t >> 2;                 // 0..63
    const int q  = t & 3;
#pragma unroll
    for (int s = 0; s < 2; ++s) {
        const int hrow = (s ? c0 + 512 : c0) + cc;
        bf16* po = hT + (long)b * HH * LL + (long)hrow * LL + r0 + q * 16;
        const uint4 w0 = *(const uint4*)&lds[s][cc][q * 8];
        const uint4 w1 = *(const uint4*)&lds[s][cc][q * 8 + 4];
        *(uint4*)(po)     = w0;
        *(uint4*)(po + 8) = w1;
    }
}

// ---------------------------------------------------------------------------
// Legacy elementwise kernels (fallback path only).
// ---------------------------------------------------------------------------
__global__ __launch_bounds__(128) void rope_kernel(
    const float* __restrict__ x, const float* __restrict__ cs,
    const float* __restrict__ sn, bf16* __restrict__ h)
{
    const int l = blockIdx.x;
    const int b = blockIdx.y;
    const int i = threadIdx.x * 4;
    const long xb = ((long)b * LL + l) * HH;
    const long cb = (long)l * HH;
    const float4 x1 = *(const float4*)(x + xb + i);
    const float4 x2 = *(const float4*)(x + xb + i + HH / 2);
    const float4 c1 = *(const float4*)(cs + cb + i);
    const float4 c2 = *(const float4*)(cs + cb + i + HH / 2);
    const float4 s1 = *(const float4*)(sn + cb + i);
    const float4 s2 = *(const float4*)(sn + cb + i + HH / 2);
    bf16x4 o1, o2;
    o1[0] = (bf16)(x1.x * c1.x - x2.x * s1.x);
    o1[1] = (bf16)(x1.y * c1.y - x2.y * s1.y);
    o1[2] = (bf16)(x1.z * c1.z - x2.z * s1.z);
    o1[3] = (bf16)(x1.w * c1.w - x2.w * s1.w);
    o2[0] = (bf16)(x2.x * c2.x + x1.x * s2.x);
    o2[1] = (bf16)(x2.y * c2.y + x1.y * s2.y);
    o2[2] = (bf16)(x2.z * c2.z + x1.z * s2.z);
    o2[3] = (bf16)(x2.w * c2.w + x1.w * s2.w);
    *(bf16x4*)(h + xb + i)          = o1;
    *(bf16x4*)(h + xb + i + HH / 2) = o2;
}

__global__ __launch_bounds__(256) void transpose_bf16_64(
    const bf16* __restrict__ in, bf16* __restrict__ out, const int R, const int C)
{
    __shared__ uint32_t lds[64][36];
    const long zoff = (long)blockIdx.z * R * C;
    const int r0 = blockIdx.x * 64;
    const int c0 = blockIdx.y * 64;
    const int t  = threadIdx.x;
    const int c8 = t & 7;
    const int rr = t >> 3;
    const bf16* p0 = in + zoff + (long)(r0 + 2 * rr) * C + c0 + c8 * 8;
    const uint4 ra = *(const uint4*)p0;
    const uint4 rb = *(const uint4*)(p0 + C);
    const uint32_t av[4] = {ra.x, ra.y, ra.z, ra.w};
    const uint32_t bv[4] = {rb.x, rb.y, rb.z, rb.w};
#pragma unroll
    for (int j = 0; j < 4; ++j) {
        const uint32_t alo = av[j] & 0xffffu, ahi = av[j] >> 16;
        const uint32_t blo = bv[j] & 0xffffu, bhi = bv[j] >> 16;
        lds[c8 * 8 + 2 * j    ][rr] = alo | (blo << 16);
        lds[c8 * 8 + 2 * j + 1][rr] = ahi | (bhi << 16);
    }
    __syncthreads();
    const int c = t >> 2;
    const int q = t & 3;
    const uint4 w0 = *(const uint4*)&lds[c][q * 8];
    const uint4 w1 = *(const uint4*)&lds[c][q * 8 + 4];
    bf16* po = out + zoff + (long)(c0 + c) * R + r0 + q * 16;
    *(uint4*)(po)     = w0;
    *(uint4*)(po + 8) = w1;
}

__global__ __launch_bounds__(256) void cast_wq(
    const float* __restrict__ Wq, bf16* __restrict__ Wb)
{
    const long idx = ((long)blockIdx.x * 256 + threadIdx.x) * 4;
    const float4 v = *(const float4*)(Wq + idx);
    bf16x4 o;
    o[0] = (bf16)v.x; o[1] = (bf16)v.y; o[2] = (bf16)v.z; o[3] = (bf16)v.w;
    *(bf16x4*)(Wb + idx) = o;
}

// ===========================================================================
// Legacy 128x128 / 2-barrier GEMM (fallback path only).
// ===========================================================================
#define GEMM_SHARED()                                                          \
    __shared__ __align__(16) bf16 As_[2][128][32];                             \
    __shared__ __align__(16) bf16 Bs_[2][128][32];

#define GEMM_PREFETCH(KOFF, BUF)                                               \
    do {                                                                       \
        async_cp16(Ag + (KOFF),           &As_[BUF][0][0] + woff0);            \
        async_cp16(Ag + (KOFF) + 64L * K, &As_[BUF][0][0] + woff1);            \
        async_cp16(Bg + (KOFF),           &Bs_[BUF][0][0] + woff0);            \
        async_cp16(Bg + (KOFF) + 64L * K, &Bs_[BUF][0][0] + woff1);            \
    } while (0)

#define GEMM_BODY(M0, N0, KBASE, KEND, DST, DT, LDN)                           \
    {                                                                          \
        const int tid  = threadIdx.x;                                          \
        const int lane = tid & 63;                                             \
        const int wave = tid >> 6;                                             \
        const int wm = (wave & 1) * 64;                                        \
        const int wn = (wave >> 1) * 64;                                       \
        const int fr = lane & 15;                                              \
        const int fq = lane >> 4;                                              \
        const int srow = tid >> 2;                                             \
        const int scol = (tid & 3) * 8;                                        \
        const int woff0 = wave * 512;                                          \
        const int woff1 = 2048 + wave * 512;                                   \
        const bf16* Ag = Ab + (long)((M0) + srow) * K + scol;                  \
        const bf16* Bg = Bb + (long)((N0) + srow) * K + scol;                  \
        const f32x4 vzero = {0.f, 0.f, 0.f, 0.f};                              \
        f32x4 acc[4][4];                                                       \
        _Pragma("unroll") for (int i = 0; i < 4; ++i)                          \
            _Pragma("unroll") for (int j = 0; j < 4; ++j) acc[i][j] = vzero;   \
        GEMM_PREFETCH(KBASE, 0);                                               \
        int buf = 0;                                                           \
        for (int k0 = (KBASE); k0 < (KEND); k0 += GBK, buf ^= 1) {             \
            __syncthreads();                                                   \
            if (k0 + GBK < (KEND)) GEMM_PREFETCH(k0 + GBK, buf ^ 1);           \
            bf16x8 af[4], bfv[4];                                              \
            _Pragma("unroll") for (int i = 0; i < 4; ++i)                      \
                af[i]  = *(const bf16x8*)&As_[buf][wm + i * 16 + fr][fq * 8];  \
            _Pragma("unroll") for (int j = 0; j < 4; ++j)                      \
                bfv[j] = *(const bf16x8*)&Bs_[buf][wn + j * 16 + fr][fq * 8];  \
            _Pragma("unroll") for (int i = 0; i < 4; ++i)                      \
                _Pragma("unroll") for (int j = 0; j < 4; ++j)                  \
                    acc[i][j] = __builtin_amdgcn_mfma_f32_16x16x32_bf16(       \
                        af[i], bfv[j], acc[i][j], 0, 0, 0);                    \
        }                                                                      \
        _Pragma("unroll") for (int i = 0; i < 4; ++i) {                        \
            _Pragma("unroll") for (int r = 0; r < 4; ++r) {                    \
                const int row = (M0) + wm + i * 16 + fq * 4 + r;               \
                _Pragma("unroll") for (int j = 0; j < 4; ++j) {                \
                    const int col = (N0) + wn + j * 16 + fr;                   \
                    (DST)[(long)row * (LDN) + col] = (DT)acc[i][j][r];         \
                }                                                              \
            }                                                                  \
        }                                                                      \
    }

template <typename OUT_T>
__global__ __launch_bounds__(256) void gemm_bt(
    const bf16* __restrict__ A, const bf16* __restrict__ B, OUT_T* __restrict__ C,
    const int M, const int N, const int K,
    const long sA, const long sB, const long sC)
{
    GEMM_SHARED();
    const bf16* Ab = A + blockIdx.z * sA;
    const bf16* Bb = B + blockIdx.z * sB;
    OUT_T*      Cb = C + blockIdx.z * sC;
    const int m0 = blockIdx.x * 128;
    const int n0 = blockIdx.y * 128;
    GEMM_BODY(m0, n0, 0, K, Cb, OUT_T, N);
}

// ===========================================================================
// 8-phase GEMM engine (T2 chunk-XOR swizzle + T3/T4 counted vmcnt + T5
// setprio). EXACT R3/R5-verified schedule: register-held B j-pairs, explicit
// lgkmcnt(0)+sched_barrier before every MFMA cluster (load-bearing — R4's
// removal regressed 40.9->65 us), identical stage/vmcnt/barrier ledger.
// ===========================================================================
#define E_STAGE_A(KT, PART, BUF)                                               \
  do {                                                                         \
    const int kk0_ = kbase + (KT) * 64;                                        \
    _Pragma("unroll") for (int qq_ = 0; qq_ < 2; ++qq_) {                      \
      const int ch_  = qq_ * 512 + tid;                                        \
      const int sl_  = ch_ >> 3;                                               \
      const int cc_  = (ch_ & 7) ^ (sl_ & 7);                                  \
      const int row_ = (sl_ & 63) + (PART) * 64 + ((sl_ >> 6) << 7);           \
      async_cp16(Ab + (long)(m0 + row_) * K + kk0_ + cc_ * 8,                  \
                 &As[BUF][PART][0][0] + (qq_ * 512 + (tid & 448)) * 8);        \
    }                                                                          \
  } while (0)

#define E_STAGE_B(KT, PART, BUF)                                               \
  do {                                                                         \
    const int kk0_ = kbase + (KT) * 64;                                        \
    _Pragma("unroll") for (int qq_ = 0; qq_ < 2; ++qq_) {                      \
      const int ch_  = qq_ * 512 + tid;                                        \
      const int sl_  = ch_ >> 3;                                               \
      const int cc_  = (ch_ & 7) ^ (sl_ & 7);                                  \
      const int row_ = (sl_ & 31) + (PART) * 32 + ((sl_ >> 5) << 6);           \
      async_cp16(Bb + (long)(n0 + row_) * K + kk0_ + cc_ * 8,                  \
                 &Bs[BUF][PART][0][0] + (qq_ * 512 + (tid & 448)) * 8);        \
    }                                                                          \
  } while (0)

#define E_STAGE_B2(KT, PART, BUF)                                              \
  do {                                                                         \
    const int kk0_ = kbase + (KT) * 64;                                        \
    const int sl_  = tid >> 3;                                                 \
    const int cc_  = (tid & 7) ^ (sl_ & 7);                                    \
    const int row_ = (sl_ & 15) + (PART) * 16 + ((sl_ >> 4) << 5);             \
    async_cp16(Bb + (long)(n0 + row_) * K + kk0_ + cc_ * 8,                    \
               &Bs2[BUF][PART][0][0] + (tid & 448) * 8);                       \
  } while (0)

#define E_LOAD_A(BUF, IG)                                                      \
  do {                                                                         \
    const bf16* Ap_ = &As[BUF][IG][0][0] + (wr * 64 + fr) * 64;                \
    _Pragma("unroll") for (int ii_ = 0; ii_ < 4; ++ii_)                        \
      _Pragma("unroll") for (int kk_ = 0; kk_ < 2; ++kk_)                      \
        af[ii_][kk_] = *(const bf16x8*)(Ap_ + ii_ * 1024 +                     \
                        (((kk_ * 4 + fq) ^ fr7) * 8));                         \
  } while (0)

#define E_LOAD_Bv(BUF, JP, DSTV)                                               \
  do {                                                                         \
    const bf16* Bp_ = &Bs[BUF][JP][0][0] + (wc * 32 + fr) * 64;                \
    _Pragma("unroll") for (int jj_ = 0; jj_ < 2; ++jj_)                        \
      _Pragma("unroll") for (int kk_ = 0; kk_ < 2; ++kk_)                      \
        DSTV[jj_][kk_] = *(const bf16x8*)(Bp_ + jj_ * 1024 +                   \
                        (((kk_ * 4 + fq) ^ fr7) * 8));                         \
  } while (0)

#define E_LOAD_B2(BUF, JG, DSTV)                                               \
  do {                                                                         \
    const bf16* Bp_ = &Bs2[BUF][JG][0][0] + (wc * 16 + fr) * 64;               \
    _Pragma("unroll") for (int kk_ = 0; kk_ < 2; ++kk_)                        \
      DSTV[kk_] = *(const bf16x8*)(Bp_ + (((kk_ * 4 + fq) ^ fr7) * 8));        \
  } while (0)

#define E_MMA(IG, JG, BV)                                                      \
  do {                                                                         \
    __builtin_amdgcn_s_setprio(1);                                             \
    _Pragma("unroll") for (int ii_ = 0; ii_ < 4; ++ii_)                        \
      _Pragma("unroll") for (int jj_ = 0; jj_ < 2; ++jj_)                      \
        _Pragma("unroll") for (int kk_ = 0; kk_ < 2; ++kk_)                    \
          acc[(IG) * 4 + ii_][(JG) * 2 + jj_] =                                \
              __builtin_amdgcn_mfma_f32_16x16x32_bf16(                         \
                  af[ii_][kk_], BV[jj_][kk_],                                  \
                  acc[(IG) * 4 + ii_][(JG) * 2 + jj_], 0, 0, 0);               \
    __builtin_amdgcn_s_setprio(0);                                             \
  } while (0)

#define E_MMA2(IG, JG, BV)                                                     \
  do {                                                                         \
    __builtin_amdgcn_s_setprio(1);                                             \
    _Pragma("unroll") for (int ii_ = 0; ii_ < 4; ++ii_)                        \
      _Pragma("unroll") for (int kk_ = 0; kk_ < 2; ++kk_)                      \
        acc2[(IG) * 4 + ii_][JG] =                                             \
            __builtin_amdgcn_mfma_f32_16x16x32_bf16(                           \
                af[ii_][kk_], BV[kk_], acc2[(IG) * 4 + ii_][JG], 0, 0, 0);     \
    __builtin_amdgcn_s_setprio(0);                                             \
  } while (0)

#define E_BAR()   __builtin_amdgcn_s_barrier()
#define E_LGKM0() do { asm volatile("s_waitcnt lgkmcnt(0)" ::: "memory");      \
                       __builtin_amdgcn_sched_barrier(0); } while (0)
#define E_VM(N)   asm volatile("s_waitcnt vmcnt(" #N ")" ::: "memory")

#define E_COMMON_IDX()                                                         \
  const int tid  = threadIdx.x;                                                \
  const int lane = tid & 63;                                                   \
  const int wv   = tid >> 6;                                                   \
  const int wr   = wv >> 2;                                                    \
  const int wc   = wv & 3;                                                     \
  const int fr   = lane & 15;                                                  \
  const int fq   = lane >> 4;                                                  \
  const int fr7  = fr & 7;                                                     \
  (void)lane;

// ---------------------------------------------------------------------------
// Merged 8-phase 256x256 kernel, 256 blocks x 512 threads (1 block/CU).
// T1 XCD-chunked remap (R3-proven). bf16 split-K partials (R5-proven).
// R6: FUSED REDUCE — per G-tile (zb,tl) atomic ticket; the 4th (last)
// split-K producer block reduces the 4 bf16 P-planes -> G in-kernel.
// Deadlock-free by construction (no spinning, order-independent); release =
// __threadfence before atomicAdd, acquire = __threadfence after prev==3.
// Replay-safe: stale tickets -> no reduction -> G keeps previous
// identical-input iteration's values (inputs are constant per bench).
// GEMM schedule = exact R3/R5 (vm(6) at P4/P8, lgkm0 before each MMA).
// ---------------------------------------------------------------------------
__global__ __launch_bounds__(512, 2) void gemm8_Gq(
    const bf16* __restrict__ hT, const bf16* __restrict__ Wb,
    const bf16* __restrict__ h, bf16* __restrict__ P, bf16* __restrict__ q,
    bf16* __restrict__ G, unsigned* __restrict__ tickets)
{
    __shared__ __align__(16) bf16 As[2][2][128][64];
    __shared__ __align__(16) bf16 Bs[2][2][128][64];
    __shared__ int lastFlag;
    E_COMMON_IDX();
    bf16x8 af[4][2], bfv0[2][2], bfv1[2][2];
    f32x4 acc[8][4];
#pragma unroll
    for (int i_ = 0; i_ < 8; ++i_)
#pragma unroll
        for (int j_ = 0; j_ < 4; ++j_) acc[i_][j_] = (f32x4){0.f, 0.f, 0.f, 0.f};

    const int bid = blockIdx.x;
    const int id  = (bid & 7) * 32 + (bid >> 3);   // XCD-chunked bijection
    const bf16* Ab; const bf16* Bb;
    int K, kbase, m0, n0;
    bf16* Cb;
    int gtick = -1, gzb = 0;
    if (id < 128) {                       // q role
        m0 = (id >> 2) * 256;             // M = B*L = 8192 (32 m-tiles)
        n0 = (id & 3) * 256;              // N = 1024 (4 n-tiles)
        Ab = h; Bb = Wb; K = HH; kbase = 0;
        Cb = q;
    } else {                              // G split-K role
        const int u  = id - 128;
        const int pl = u >> 4;            // plane 0..7 = zb*4+zs
        const int zb = pl >> 2;
        const int zs = pl & 3;
        const int tl = u & 15;
        m0 = (tl & 3) * 256;
        n0 = (tl >> 2) * 256;
        Ab = hT + (long)zb * HH * LL; Bb = Ab;
        K  = LL; kbase = zs * (LL / 4);
        Cb = P + (long)pl * HH * HH;
        gtick = zb * 16 + tl; gzb = zb;
    }

    // prologue: tile0 fully + tile1's first 3 halves; drain tile0.
    E_STAGE_A(0, 0, 0); E_STAGE_B(0, 1, 0); E_STAGE_A(0, 1, 0);
    E_STAGE_B(0, 0, 0);
    E_STAGE_A(1, 0, 1); E_STAGE_B(1, 1, 1); E_STAGE_A(1, 1, 1);
    E_VM(6); E_BAR();
    int t_ = 0;
#pragma unroll 1
    for (; t_ + 3 < 16; t_ += 2) {
        /* P1 */ E_LOAD_A(0, 0); E_LOAD_Bv(0, 0, bfv0); E_STAGE_B(t_ + 1, 0, 1);
                 E_BAR(); E_LGKM0(); E_MMA(0, 0, bfv0); E_BAR();
        /* P2 */ E_LOAD_Bv(0, 1, bfv1); E_STAGE_A(t_ + 2, 0, 0);
                 E_BAR(); E_LGKM0(); E_MMA(0, 1, bfv1); E_BAR();
        /* P3 */ E_LOAD_A(0, 1); E_STAGE_B(t_ + 2, 1, 0);
                 E_BAR(); E_LGKM0(); E_MMA(1, 1, bfv1); E_BAR();
        /* P4 */ E_STAGE_A(t_ + 2, 1, 0);
                 E_MMA(1, 0, bfv0); E_VM(6); E_BAR();
        /* P5 */ E_LOAD_A(1, 0); E_LOAD_Bv(1, 0, bfv0); E_STAGE_B(t_ + 2, 0, 0);
                 E_BAR(); E_LGKM0(); E_MMA(0, 0, bfv0); E_BAR();
        /* P6 */ E_LOAD_Bv(1, 1, bfv1); E_STAGE_A(t_ + 3, 0, 1);
                 E_BAR(); E_LGKM0(); E_MMA(0, 1, bfv1); E_BAR();
        /* P7 */ E_LOAD_A(1, 1); E_STAGE_B(t_ + 3, 1, 1);
                 E_BAR(); E_LGKM0(); E_MMA(1, 1, bfv1); E_BAR();
        /* P8 */ E_STAGE_A(t_ + 3, 1, 1);
                 E_MMA(1, 0, bfv0); E_VM(6); E_BAR();
    }
    // epilogue pair: only B(NT-1)p0 left to stage
    E_LOAD_A(0, 0); E_LOAD_Bv(0, 0, bfv0); E_STAGE_B(t_ + 1, 0, 1);
    E_BAR(); E_LGKM0(); E_MMA(0, 0, bfv0); E_BAR();
    E_LOAD_Bv(0, 1, bfv1); E_BAR(); E_LGKM0(); E_MMA(0, 1, bfv1); E_BAR();
    E_LOAD_A(0, 1); E_BAR(); E_LGKM0(); E_MMA(1, 1, bfv1); E_BAR();
    E_MMA(1, 0, bfv0); E_VM(0); E_BAR();
    E_LOAD_A(1, 0); E_LOAD_Bv(1, 0, bfv0); E_BAR(); E_LGKM0(); E_MMA(0, 0, bfv0); E_BAR();
    E_LOAD_Bv(1, 1, bfv1); E_BAR(); E_LGKM0(); E_MMA(0, 1, bfv1); E_BAR();
    E_LOAD_A(1, 1); E_BAR(); E_LGKM0(); E_MMA(1, 1, bfv1); E_BAR();
    E_MMA(1, 0, bfv0);

    // C/D layout per 16x16 frag: col = lane&15 (fr), row = (lane>>4)*4 + reg.
#pragma unroll
    for (int gi = 0; gi < 8; ++gi)
#pragma unroll
        for (int r = 0; r < 4; ++r) {
            const int row = m0 + wr * 128 + gi * 16 + fq * 4 + r;
#pragma unroll
            for (int gj = 0; gj < 4; ++gj)
                Cb[(long)row * HH + n0 + wc * 64 + gj * 16 + fr] = (bf16)acc[gi][gj][r];
        }

    // ---- fused split-K reduce: last arriver of this G-tile sums 4 planes.
    if (gtick >= 0) {
        __threadfence();                       // release this block's P-tile
        if (tid == 0) {
            const unsigned prev = atomicAdd(&tickets[gtick], 1u);
            lastFlag = (prev == 3u);
        }
        __syncthreads();
        if (lastFlag) {
            __threadfence();                   // acquire other planes' stores
            const bf16* P0 = P + (long)(gzb * 4) * HH * HH;
            bf16* Gb = G + (long)gzb * HH * HH;
            const int row  = tid >> 1;                         // 0..255
            const long base = (long)(m0 + row) * HH + n0 + (tid & 1) * 128;
#pragma unroll
            for (int v = 0; v < 16; ++v) {
                const long off = base + v * 8;
                float a[8];
                const bf16x8 v0 = *(const bf16x8*)(P0 + off);
                const bf16x8 v1 = *(const bf16x8*)(P0 + off + (long)1 * HH * HH);
                const bf16x8 v2 = *(const bf16x8*)(P0 + off + (long)2 * HH * HH);
                const bf16x8 v3 = *(const bf16x8*)(P0 + off + (long)3 * HH * HH);
#pragma unroll
                for (int j = 0; j < 8; ++j)
                    a[j] = (float)v0[j] + (float)v1[j] + (float)v2[j] + (float)v3[j];
                bf16x8 o;
#pragma unroll
                for (int j = 0; j < 8; ++j) o[j] = (bf16)a[j];
                *(bf16x8*)(Gb + off) = o;
            }
        }
    }
}

// ---------------------------------------------------------------------------
// O_b = q_b · G_b^T (G symmetric -> exact). 8-phase BM=256 x BN=128 engine,
// 256 blocks x 512 threads, T1 remap. EXACT R3 schedule: vm(5) at P4/P8.
// ---------------------------------------------------------------------------
__global__ __launch_bounds__(512, 2) void gemm8_qG(
    const bf16* __restrict__ qm, const bf16* __restrict__ G, float* __restrict__ out)
{
    __shared__ __align__(16) bf16 As[2][2][128][64];
    __shared__ __align__(16) bf16 Bs2[2][2][64][64];
    E_COMMON_IDX();
    bf16x8 af[4][2], bw0[2], bw1[2];
    f32x4 acc2[8][2];
#pragma unroll
    for (int i_ = 0; i_ < 8; ++i_)
#pragma unroll
        for (int j_ = 0; j_ < 2; ++j_) acc2[i_][j_] = (f32x4){0.f, 0.f, 0.f, 0.f};

    const int bid = blockIdx.x;
    const int id  = (bid & 7) * 32 + (bid >> 3);   // XCD-chunked bijection
    const int mb  = id >> 3;              // 0..31: batch*16 + m-tile
    const int b   = mb >> 4;
    const int m0  = (mb & 15) * 256;
    const int n0  = (id & 7) * 128;
    const bf16* Ab = qm + (long)b * LL * HH;
    const bf16* Bb = G + (long)b * HH * HH;
    const int K = HH, kbase = 0;
    float* outb = out + (long)b * LL * HH;

    // prologue: tile0 fully + tile1's A halves + B p1; drain tile0 (vm(5)).
    E_STAGE_A(0, 0, 0); E_STAGE_B2(0, 1, 0); E_STAGE_A(0, 1, 0);
    E_STAGE_B2(0, 0, 0);
    E_STAGE_A(1, 0, 1); E_STAGE_B2(1, 1, 1); E_STAGE_A(1, 1, 1);
    E_VM(5); E_BAR();
    int t_ = 0;
#pragma unroll 1
    for (; t_ + 3 < 16; t_ += 2) {
        /* P1 */ E_LOAD_A(0, 0); E_LOAD_B2(0, 0, bw0); E_STAGE_B2(t_ + 1, 0, 1);
                 E_BAR(); E_LGKM0(); E_MMA2(0, 0, bw0); E_BAR();
        /* P2 */ E_LOAD_B2(0, 1, bw1); E_STAGE_A(t_ + 2, 0, 0);
                 E_BAR(); E_LGKM0(); E_MMA2(0, 1, bw1); E_BAR();
        /* P3 */ E_LOAD_A(0, 1); E_STAGE_B2(t_ + 2, 1, 0);
                 E_BAR(); E_LGKM0(); E_MMA2(1, 1, bw1); E_BAR();
        /* P4 */ E_STAGE_A(t_ + 2, 1, 0);
                 E_MMA2(1, 0, bw0); E_VM(5); E_BAR();
        /* P5 */ E_LOAD_A(1, 0); E_LOAD_B2(1, 0, bw0); E_STAGE_B2(t_ + 2, 0, 0);
                 E_BAR(); E_LGKM0(); E_MMA2(0, 0, bw0); E_BAR();
        /* P6 */ E_LOAD_B2(1, 1, bw1); E_STAGE_A(t_ + 3, 0, 1);
                 E_BAR(); E_LGKM0(); E_MMA2(0, 1, bw1); E_BAR();
        /* P7 */ E_LOAD_A(1, 1); E_STAGE_B2(t_ + 3, 1, 1);
                 E_BAR(); E_LGKM0(); E_MMA2(1, 1, bw1); E_BAR();
        /* P8 */ E_STAGE_A(t_ + 3, 1, 1);
                 E_MMA2(1, 0, bw0); E_VM(5); E_BAR();
    }
    // epilogue pair
    E_LOAD_A(0, 0); E_LOAD_B2(0, 0, bw0); E_STAGE_B2(t_ + 1, 0, 1);
    E_BAR(); E_LGKM0(); E_MMA2(0, 0, bw0); E_BAR();
    E_LOAD_B2(0, 1, bw1); E_BAR(); E_LGKM0(); E_MMA2(0, 1, bw1); E_BAR();
    E_LOAD_A(0, 1); E_BAR(); E_LGKM0(); E_MMA2(1, 1, bw1); E_BAR();
    E_MMA2(1, 0, bw0); E_VM(0); E_BAR();
    E_LOAD_A(1, 0); E_LOAD_B2(1, 0, bw0); E_BAR(); E_LGKM0(); E_MMA2(0, 0, bw0); E_BAR();
    E_LOAD_B2(1, 1, bw1); E_BAR(); E_LGKM0(); E_MMA2(0, 1, bw1); E_BAR();
    E_LOAD_A(1, 1); E_BAR(); E_LGKM0(); E_MMA2(1, 1, bw1); E_BAR();
    E_MMA2(1, 0, bw0);

#pragma unroll
    for (int gi = 0; gi < 8; ++gi)
#pragma unroll
        for (int r = 0; r < 4; ++r) {
            const int row = m0 + wr * 128 + gi * 16 + fq * 4 + r;
#pragma unroll
            for (int gj = 0; gj < 2; ++gj)
                outb[(long)row * HH + n0 + wc * 32 + gj * 16 + fr] = acc2[gi][gj][r];
        }
}

// ---------------------------------------------------------------------------
// Pipeline (3 dispatches): prep (RoPE+transpose+cast+ticket-zero);
//   merged 8-phase Gq (bf16 partials + fused ticket-reduce -> G);
//   qG (O = q·G).
// Workspace: h@0 (16M) | hT@16M | Wb@32M | G@34M | P@38M (16M bf16) |
//            q@70M (16M) | tickets@87M (128 B)
// ---------------------------------------------------------------------------
extern "C" void kernel_launch(void* const* d_in, const int* in_sizes, int n_in,
                              void* d_out, int out_size, void* d_ws, size_t ws_size,
                              hipStream_t stream)
{
    const float* x  = (const float*)d_in[0];   // hidden_states [B,L,H]
    const float* Wq = (const float*)d_in[1];   // [H,H]
    const float* cs = (const float*)d_in[2];   // [L,H]
    const float* sn = (const float*)d_in[3];   // [L,H]
    float* out = (float*)d_out;                // [B,L,H] fp32
    char* ws = (char*)d_ws;

    bf16*  h  = (bf16*)(ws);
    bf16*  hT = (bf16*)(ws + 16u * 1024 * 1024);
    bf16*  Wb = (bf16*)(ws + 32u * 1024 * 1024);
    bf16*  G  = (bf16*)(ws + 34u * 1024 * 1024);
    bf16*  P  = (bf16*)(ws + 38u * 1024 * 1024);   // 8 planes of H*H bf16

    const bool big_ws = ws_size >= (size_t)90 * 1024 * 1024;
    bf16* q = big_ws ? (bf16*)(ws + 70u * 1024 * 1024)
                     : (bf16*)(ws + 54u * 1024 * 1024);  // fallback: after P
    unsigned* tickets = (unsigned*)(ws + 87u * 1024 * 1024);

    if (big_ws) {
        // 1) fused RoPE + transpose + Wq cast + ticket zero
        prep_kernel<<<dim3(1280), 256, 0, stream>>>(x, cs, sn, Wq, h, hT, Wb, tickets);
        // 2) merged 8-phase: G split-K partials + fused reduce + q GEMM
        gemm8_Gq<<<dim3(256), 512, 0, stream>>>(hT, Wb, h, P, q, G, tickets);
        // 3) O_b = q_b @ G_b, 8-phase 256-block engine
        gemm8_qG<<<dim3(256), 512, 0, stream>>>(q, G, out);
    } else {
        rope_kernel<<<dim3(LL, BB), 128, 0, stream>>>(x, cs, sn, h);
        transpose_bf16_64<<<dim3(LL / 64, HH / 64, BB), 256, 0, stream>>>(h, hT, LL, HH);
        cast_wq<<<dim3(HH * HH / 1024), 256, 0, stream>>>(Wq, Wb);
        gemm_bt<bf16><<<dim3(HH / 128, HH / 128, BB), 256, 0, stream>>>(
            hT, hT, G, HH, HH, LL, (long)HH * LL, (long)HH * LL, (long)HH * HH);
        gemm_bt<bf16><<<dim3(LL / 128, HH / 128, BB), 256, 0, stream>>>(
            h, Wb, q, LL, HH, HH, (long)LL * HH, 0L, (long)LL * HH);
        gemm_bt<float><<<dim3(LL / 128, HH / 128, BB), 256, 0, stream>>>(
            q, G, out, LL, HH, HH, (long)LL * HH, (long)HH * HH, (long)LL * HH);
    }
}

// Round 7
// 167.713 us; speedup vs baseline: 1.7709x; 1.7709x over previous
//
#include <hip/hip_runtime.h>
#include <hip/hip_bf16.h>
#include <stdint.h>

// Problem constants (from reference): B=2, L=4096, H=1024
#define BB 2
#define LL 4096
#define HH 1024
#define GBK 32   // fallback GEMM K-tile

typedef __bf16 bf16;
typedef __bf16 bf16x4 __attribute__((ext_vector_type(4)));
typedef __bf16 bf16x8 __attribute__((ext_vector_type(8)));
typedef float  f32x4  __attribute__((ext_vector_type(4)));

// ---------------------------------------------------------------------------
// async global->LDS, 16 B per lane (m104/m108 semantics).
// ---------------------------------------------------------------------------
__device__ __forceinline__ void async_cp16(const bf16* g, const bf16* l)
{
    typedef const uint32_t __attribute__((address_space(1)))* gp_t;
    typedef uint32_t __attribute__((address_space(3)))* lp_t;
    __builtin_amdgcn_global_load_lds((gp_t)(uintptr_t)g, (lp_t)(uintptr_t)l, 16, 0, 0);
}

__device__ __forceinline__ uint32_t pack_bf16(float lo, float hi)
{
    union { bf16 b; unsigned short u; } a, c;
    a.b = (bf16)lo; c.b = (bf16)hi;
    return (uint32_t)a.u | ((uint32_t)c.u << 16);
}

// ---------------------------------------------------------------------------
// FUSED prep kernel: RoPE (fp32 -> bf16 h), transpose (h -> hT), Wq cast.
// cos/sin dedup: cos[l, i+512] == cos[l, i] (emb = concat([freqs, freqs])).
// R7: BATCH-PAIRING — tables are batch-invariant; each tile block processes
// BOTH batches for its (r0,c0) tile, loading cos/sin registers ONCE
// (-16 MB HBM vs R5; identical math/outputs). 512 tile blocks + 256 cast.
// ---------------------------------------------------------------------------
__global__ __launch_bounds__(256) void prep_kernel(
    const float* __restrict__ x, const float* __restrict__ cs,
    const float* __restrict__ sn, const float* __restrict__ Wq,
    bf16* __restrict__ h, bf16* __restrict__ hT, bf16* __restrict__ Wb)
{
    const int id = blockIdx.x;
    if (id >= 512) {                       // ---- Wq cast tail: 256 blocks
        const long base = (long)(id - 512) * 4096 + (long)threadIdx.x * 16;
#pragma unroll
        for (int j = 0; j < 4; ++j) {
            const float4 v = *(const float4*)(Wq + base + j * 4);
            bf16x4 o;
            o[0] = (bf16)v.x; o[1] = (bf16)v.y; o[2] = (bf16)v.z; o[3] = (bf16)v.w;
            *(bf16x4*)(Wb + base + j * 4) = o;
        }
        return;
    }
    __shared__ uint32_t lds[2][64][36];    // [strip][col][row-pair], 18 KiB
    const int r0 = (id >> 3) * 64;
    const int c0 = (id & 7) * 64;          // strip A cols [c0,c0+64); B = +512
    const int t  = threadIdx.x;
    const int c8 = t & 7;                  // col octet within strip
    const int rr = t >> 3;                 // row pair 0..31
    const int ca = c0 + c8 * 8;
    const long crow0 = (long)(r0 + 2 * rr) * HH;

    // load batch-invariant tables once (first-half cols only, dedup)
    float cA[2][8], sA[2][8];
#pragma unroll
    for (int rw = 0; rw < 2; ++rw) {
        const long cr = crow0 + (long)rw * HH;
        *(float4*)&cA[rw][0] = *(const float4*)(cs + cr + ca);
        *(float4*)&cA[rw][4] = *(const float4*)(cs + cr + ca + 4);
        *(float4*)&sA[rw][0] = *(const float4*)(sn + cr + ca);
        *(float4*)&sA[rw][4] = *(const float4*)(sn + cr + ca + 4);
    }

    for (int b = 0; b < 2; ++b) {
        if (b) __syncthreads();            // prev pass's lds reads complete
        float oA[2][8], oB[2][8];
#pragma unroll
        for (int rw = 0; rw < 2; ++rw) {
            const long xr = ((long)b * LL + r0 + 2 * rr + rw) * HH;
            float xA[8], xB[8];
            *(float4*)&xA[0] = *(const float4*)(x + xr + ca);
            *(float4*)&xA[4] = *(const float4*)(x + xr + ca + 4);
            *(float4*)&xB[0] = *(const float4*)(x + xr + ca + 512);
            *(float4*)&xB[4] = *(const float4*)(x + xr + ca + 516);
#pragma unroll
            for (int j = 0; j < 8; ++j) {
                oA[rw][j] = xA[j] * cA[rw][j] - xB[j] * sA[rw][j];  // first half
                oB[rw][j] = xB[j] * cA[rw][j] + xA[j] * sA[rw][j];  // second half
            }
            bf16x8 hA, hB;
#pragma unroll
            for (int j = 0; j < 8; ++j) { hA[j] = (bf16)oA[rw][j]; hB[j] = (bf16)oB[rw][j]; }
            *(bf16x8*)(h + xr + ca)       = hA;
            *(bf16x8*)(h + xr + ca + 512) = hB;
        }
#pragma unroll
        for (int j = 0; j < 8; ++j) {
            lds[0][c8 * 8 + j][rr] = pack_bf16(oA[0][j], oA[1][j]);
            lds[1][c8 * 8 + j][rr] = pack_bf16(oB[0][j], oB[1][j]);
        }
        __syncthreads();

        const int cc = t >> 2;             // 0..63
        const int q  = t & 3;
#pragma unroll
        for (int s = 0; s < 2; ++s) {
            const int hrow = (s ? c0 + 512 : c0) + cc;
            bf16* po = hT + (long)b * HH * LL + (long)hrow * LL + r0 + q * 16;
            const uint4 w0 = *(const uint4*)&lds[s][cc][q * 8];
            const uint4 w1 = *(const uint4*)&lds[s][cc][q * 8 + 4];
            *(uint4*)(po)     = w0;
            *(uint4*)(po + 8) = w1;
        }
    }
}

// ---------------------------------------------------------------------------
// Legacy elementwise kernels (fallback path only).
// ---------------------------------------------------------------------------
__global__ __launch_bounds__(128) void rope_kernel(
    const float* __restrict__ x, const float* __restrict__ cs,
    const float* __restrict__ sn, bf16* __restrict__ h)
{
    const int l = blockIdx.x;
    const int b = blockIdx.y;
    const int i = threadIdx.x * 4;
    const long xb = ((long)b * LL + l) * HH;
    const long cb = (long)l * HH;
    const float4 x1 = *(const float4*)(x + xb + i);
    const float4 x2 = *(const float4*)(x + xb + i + HH / 2);
    const float4 c1 = *(const float4*)(cs + cb + i);
    const float4 c2 = *(const float4*)(cs + cb + i + HH / 2);
    const float4 s1 = *(const float4*)(sn + cb + i);
    const float4 s2 = *(const float4*)(sn + cb + i + HH / 2);
    bf16x4 o1, o2;
    o1[0] = (bf16)(x1.x * c1.x - x2.x * s1.x);
    o1[1] = (bf16)(x1.y * c1.y - x2.y * s1.y);
    o1[2] = (bf16)(x1.z * c1.z - x2.z * s1.z);
    o1[3] = (bf16)(x1.w * c1.w - x2.w * s1.w);
    o2[0] = (bf16)(x2.x * c2.x + x1.x * s2.x);
    o2[1] = (bf16)(x2.y * c2.y + x1.y * s2.y);
    o2[2] = (bf16)(x2.z * c2.z + x1.z * s2.z);
    o2[3] = (bf16)(x2.w * c2.w + x1.w * s2.w);
    *(bf16x4*)(h + xb + i)          = o1;
    *(bf16x4*)(h + xb + i + HH / 2) = o2;
}

__global__ __launch_bounds__(256) void transpose_bf16_64(
    const bf16* __restrict__ in, bf16* __restrict__ out, const int R, const int C)
{
    __shared__ uint32_t lds[64][36];
    const long zoff = (long)blockIdx.z * R * C;
    const int r0 = blockIdx.x * 64;
    const int c0 = blockIdx.y * 64;
    const int t  = threadIdx.x;
    const int c8 = t & 7;
    const int rr = t >> 3;
    const bf16* p0 = in + zoff + (long)(r0 + 2 * rr) * C + c0 + c8 * 8;
    const uint4 ra = *(const uint4*)p0;
    const uint4 rb = *(const uint4*)(p0 + C);
    const uint32_t av[4] = {ra.x, ra.y, ra.z, ra.w};
    const uint32_t bv[4] = {rb.x, rb.y, rb.z, rb.w};
#pragma unroll
    for (int j = 0; j < 4; ++j) {
        const uint32_t alo = av[j] & 0xffffu, ahi = av[j] >> 16;
        const uint32_t blo = bv[j] & 0xffffu, bhi = bv[j] >> 16;
        lds[c8 * 8 + 2 * j    ][rr] = alo | (blo << 16);
        lds[c8 * 8 + 2 * j + 1][rr] = ahi | (bhi << 16);
    }
    __syncthreads();
    const int c = t >> 2;
    const int q = t & 3;
    const uint4 w0 = *(const uint4*)&lds[c][q * 8];
    const uint4 w1 = *(const uint4*)&lds[c][q * 8 + 4];
    bf16* po = out + zoff + (long)(c0 + c) * R + r0 + q * 16;
    *(uint4*)(po)     = w0;
    *(uint4*)(po + 8) = w1;
}

__global__ __launch_bounds__(256) void cast_wq(
    const float* __restrict__ Wq, bf16* __restrict__ Wb)
{
    const long idx = ((long)blockIdx.x * 256 + threadIdx.x) * 4;
    const float4 v = *(const float4*)(Wq + idx);
    bf16x4 o;
    o[0] = (bf16)v.x; o[1] = (bf16)v.y; o[2] = (bf16)v.z; o[3] = (bf16)v.w;
    *(bf16x4*)(Wb + idx) = o;
}

// ===========================================================================
// Legacy 128x128 / 2-barrier GEMM (fallback path only).
// ===========================================================================
#define GEMM_SHARED()                                                          \
    __shared__ __align__(16) bf16 As_[2][128][32];                             \
    __shared__ __align__(16) bf16 Bs_[2][128][32];

#define GEMM_PREFETCH(KOFF, BUF)                                               \
    do {                                                                       \
        async_cp16(Ag + (KOFF),           &As_[BUF][0][0] + woff0);            \
        async_cp16(Ag + (KOFF) + 64L * K, &As_[BUF][0][0] + woff1);            \
        async_cp16(Bg + (KOFF),           &Bs_[BUF][0][0] + woff0);            \
        async_cp16(Bg + (KOFF) + 64L * K, &Bs_[BUF][0][0] + woff1);            \
    } while (0)

#define GEMM_BODY(M0, N0, KBASE, KEND, DST, DT, LDN)                           \
    {                                                                          \
        const int tid  = threadIdx.x;                                          \
        const int lane = tid & 63;                                             \
        const int wave = tid >> 6;                                             \
        const int wm = (wave & 1) * 64;                                        \
        const int wn = (wave >> 1) * 64;                                       \
        const int fr = lane & 15;                                              \
        const int fq = lane >> 4;                                              \
        const int srow = tid >> 2;                                             \
        const int scol = (tid & 3) * 8;                                        \
        const int woff0 = wave * 512;                                          \
        const int woff1 = 2048 + wave * 512;                                   \
        const bf16* Ag = Ab + (long)((M0) + srow) * K + scol;                  \
        const bf16* Bg = Bb + (long)((N0) + srow) * K + scol;                  \
        const f32x4 vzero = {0.f, 0.f, 0.f, 0.f};                              \
        f32x4 acc[4][4];                                                       \
        _Pragma("unroll") for (int i = 0; i < 4; ++i)                          \
            _Pragma("unroll") for (int j = 0; j < 4; ++j) acc[i][j] = vzero;   \
        GEMM_PREFETCH(KBASE, 0);                                               \
        int buf = 0;                                                           \
        for (int k0 = (KBASE); k0 < (KEND); k0 += GBK, buf ^= 1) {             \
            __syncthreads();                                                   \
            if (k0 + GBK < (KEND)) GEMM_PREFETCH(k0 + GBK, buf ^ 1);           \
            bf16x8 af[4], bfv[4];                                              \
            _Pragma("unroll") for (int i = 0; i < 4; ++i)                      \
                af[i]  = *(const bf16x8*)&As_[buf][wm + i * 16 + fr][fq * 8];  \
            _Pragma("unroll") for (int j = 0; j < 4; ++j)                      \
                bfv[j] = *(const bf16x8*)&Bs_[buf][wn + j * 16 + fr][fq * 8];  \
            _Pragma("unroll") for (int i = 0; i < 4; ++i)                      \
                _Pragma("unroll") for (int j = 0; j < 4; ++j)                  \
                    acc[i][j] = __builtin_amdgcn_mfma_f32_16x16x32_bf16(       \
                        af[i], bfv[j], acc[i][j], 0, 0, 0);                    \
        }                                                                      \
        _Pragma("unroll") for (int i = 0; i < 4; ++i) {                        \
            _Pragma("unroll") for (int r = 0; r < 4; ++r) {                    \
                const int row = (M0) + wm + i * 16 + fq * 4 + r;               \
                _Pragma("unroll") for (int j = 0; j < 4; ++j) {                \
                    const int col = (N0) + wn + j * 16 + fr;                   \
                    (DST)[(long)row * (LDN) + col] = (DT)acc[i][j][r];         \
                }                                                              \
            }                                                                  \
        }                                                                      \
    }

template <typename OUT_T>
__global__ __launch_bounds__(256) void gemm_bt(
    const bf16* __restrict__ A, const bf16* __restrict__ B, OUT_T* __restrict__ C,
    const int M, const int N, const int K,
    const long sA, const long sB, const long sC)
{
    GEMM_SHARED();
    const bf16* Ab = A + blockIdx.z * sA;
    const bf16* Bb = B + blockIdx.z * sB;
    OUT_T*      Cb = C + blockIdx.z * sC;
    const int m0 = blockIdx.x * 128;
    const int n0 = blockIdx.y * 128;
    GEMM_BODY(m0, n0, 0, K, Cb, OUT_T, N);
}

// ===========================================================================
// 8-phase GEMM engine (T2 chunk-XOR swizzle + T3/T4 counted vmcnt + T5
// setprio). EXACT R3/R5-verified schedule: register-held B j-pairs, explicit
// lgkmcnt(0)+sched_barrier before every MFMA cluster (load-bearing — R4's
// removal regressed 40.9->65 us), identical stage/vmcnt/barrier ledger.
// R6 lesson: NO device-scope fences / cross-block dataflow in-kernel — the
// per-XCD L2 writeback storm cost 124 us. Producer/consumer stays at the
// kernel-launch boundary.
// ===========================================================================
#define E_STAGE_A(KT, PART, BUF)                                               \
  do {                                                                         \
    const int kk0_ = kbase + (KT) * 64;                                        \
    _Pragma("unroll") for (int qq_ = 0; qq_ < 2; ++qq_) {                      \
      const int ch_  = qq_ * 512 + tid;                                        \
      const int sl_  = ch_ >> 3;                                               \
      const int cc_  = (ch_ & 7) ^ (sl_ & 7);                                  \
      const int row_ = (sl_ & 63) + (PART) * 64 + ((sl_ >> 6) << 7);           \
      async_cp16(Ab + (long)(m0 + row_) * K + kk0_ + cc_ * 8,                  \
                 &As[BUF][PART][0][0] + (qq_ * 512 + (tid & 448)) * 8);        \
    }                                                                          \
  } while (0)

#define E_STAGE_B(KT, PART, BUF)                                               \
  do {                                                                         \
    const int kk0_ = kbase + (KT) * 64;                                        \
    _Pragma("unroll") for (int qq_ = 0; qq_ < 2; ++qq_) {                      \
      const int ch_  = qq_ * 512 + tid;                                        \
      const int sl_  = ch_ >> 3;                                               \
      const int cc_  = (ch_ & 7) ^ (sl_ & 7);                                  \
      const int row_ = (sl_ & 31) + (PART) * 32 + ((sl_ >> 5) << 6);           \
      async_cp16(Bb + (long)(n0 + row_) * K + kk0_ + cc_ * 8,                  \
                 &Bs[BUF][PART][0][0] + (qq_ * 512 + (tid & 448)) * 8);        \
    }                                                                          \
  } while (0)

#define E_STAGE_B2(KT, PART, BUF)                                              \
  do {                                                                         \
    const int kk0_ = kbase + (KT) * 64;                                        \
    const int sl_  = tid >> 3;                                                 \
    const int cc_  = (tid & 7) ^ (sl_ & 7);                                    \
    const int row_ = (sl_ & 15) + (PART) * 16 + ((sl_ >> 4) << 5);             \
    async_cp16(Bb + (long)(n0 + row_) * K + kk0_ + cc_ * 8,                    \
               &Bs2[BUF][PART][0][0] + (tid & 448) * 8);                       \
  } while (0)

#define E_LOAD_A(BUF, IG)                                                      \
  do {                                                                         \
    const bf16* Ap_ = &As[BUF][IG][0][0] + (wr * 64 + fr) * 64;                \
    _Pragma("unroll") for (int ii_ = 0; ii_ < 4; ++ii_)                        \
      _Pragma("unroll") for (int kk_ = 0; kk_ < 2; ++kk_)                      \
        af[ii_][kk_] = *(const bf16x8*)(Ap_ + ii_ * 1024 +                     \
                        (((kk_ * 4 + fq) ^ fr7) * 8));                         \
  } while (0)

#define E_LOAD_Bv(BUF, JP, DSTV)                                               \
  do {                                                                         \
    const bf16* Bp_ = &Bs[BUF][JP][0][0] + (wc * 32 + fr) * 64;                \
    _Pragma("unroll") for (int jj_ = 0; jj_ < 2; ++jj_)                        \
      _Pragma("unroll") for (int kk_ = 0; kk_ < 2; ++kk_)                      \
        DSTV[jj_][kk_] = *(const bf16x8*)(Bp_ + jj_ * 1024 +                   \
                        (((kk_ * 4 + fq) ^ fr7) * 8));                         \
  } while (0)

#define E_LOAD_B2(BUF, JG, DSTV)                                               \
  do {                                                                         \
    const bf16* Bp_ = &Bs2[BUF][JG][0][0] + (wc * 16 + fr) * 64;               \
    _Pragma("unroll") for (int kk_ = 0; kk_ < 2; ++kk_)                        \
      DSTV[kk_] = *(const bf16x8*)(Bp_ + (((kk_ * 4 + fq) ^ fr7) * 8));        \
  } while (0)

#define E_MMA(IG, JG, BV)                                                      \
  do {                                                                         \
    __builtin_amdgcn_s_setprio(1);                                             \
    _Pragma("unroll") for (int ii_ = 0; ii_ < 4; ++ii_)                        \
      _Pragma("unroll") for (int jj_ = 0; jj_ < 2; ++jj_)                      \
        _Pragma("unroll") for (int kk_ = 0; kk_ < 2; ++kk_)                    \
          acc[(IG) * 4 + ii_][(JG) * 2 + jj_] =                                \
              __builtin_amdgcn_mfma_f32_16x16x32_bf16(                         \
                  af[ii_][kk_], BV[jj_][kk_],                                  \
                  acc[(IG) * 4 + ii_][(JG) * 2 + jj_], 0, 0, 0);               \
    __builtin_amdgcn_s_setprio(0);                                             \
  } while (0)

#define E_MMA2(IG, JG, BV)                                                     \
  do {                                                                         \
    __builtin_amdgcn_s_setprio(1);                                             \
    _Pragma("unroll") for (int ii_ = 0; ii_ < 4; ++ii_)                        \
      _Pragma("unroll") for (int kk_ = 0; kk_ < 2; ++kk_)                      \
        acc2[(IG) * 4 + ii_][JG] =                                             \
            __builtin_amdgcn_mfma_f32_16x16x32_bf16(                           \
                af[ii_][kk_], BV[kk_], acc2[(IG) * 4 + ii_][JG], 0, 0, 0);     \
    __builtin_amdgcn_s_setprio(0);                                             \
  } while (0)

#define E_BAR()   __builtin_amdgcn_s_barrier()
#define E_LGKM0() do { asm volatile("s_waitcnt lgkmcnt(0)" ::: "memory");      \
                       __builtin_amdgcn_sched_barrier(0); } while (0)
#define E_VM(N)   asm volatile("s_waitcnt vmcnt(" #N ")" ::: "memory")

#define E_COMMON_IDX()                                                         \
  const int tid  = threadIdx.x;                                                \
  const int lane = tid & 63;                                                   \
  const int wv   = tid >> 6;                                                   \
  const int wr   = wv >> 2;                                                    \
  const int wc   = wv & 3;                                                     \
  const int fr   = lane & 15;                                                  \
  const int fq   = lane >> 4;                                                  \
  const int fr7  = fr & 7;                                                     \
  (void)lane;

// ---------------------------------------------------------------------------
// Merged 8-phase 256x256 kernel, 256 blocks x 512 threads (1 block/CU).
// T1 XCD-chunked remap (R3-proven). bf16 split-K partials (R5-proven).
// Schedule = exact R3/R5 (vm(6) at P4/P8, lgkm0 before each MMA).
// ---------------------------------------------------------------------------
__global__ __launch_bounds__(512, 2) void gemm8_Gq(
    const bf16* __restrict__ hT, const bf16* __restrict__ Wb,
    const bf16* __restrict__ h, bf16* __restrict__ P, bf16* __restrict__ q)
{
    __shared__ __align__(16) bf16 As[2][2][128][64];
    __shared__ __align__(16) bf16 Bs[2][2][128][64];
    E_COMMON_IDX();
    bf16x8 af[4][2], bfv0[2][2], bfv1[2][2];
    f32x4 acc[8][4];
#pragma unroll
    for (int i_ = 0; i_ < 8; ++i_)
#pragma unroll
        for (int j_ = 0; j_ < 4; ++j_) acc[i_][j_] = (f32x4){0.f, 0.f, 0.f, 0.f};

    const int bid = blockIdx.x;
    const int id  = (bid & 7) * 32 + (bid >> 3);   // XCD-chunked bijection
    const bf16* Ab; const bf16* Bb;
    int K, kbase, m0, n0;
    bf16* Cb;
    if (id < 128) {                       // q role
        m0 = (id >> 2) * 256;             // M = B*L = 8192 (32 m-tiles)
        n0 = (id & 3) * 256;              // N = 1024 (4 n-tiles)
        Ab = h; Bb = Wb; K = HH; kbase = 0;
        Cb = q;
    } else {                              // G split-K role
        const int u  = id - 128;
        const int pl = u >> 4;            // plane 0..7 = zb*4+zs
        const int zb = pl >> 2;
        const int zs = pl & 3;
        const int tl = u & 15;
        m0 = (tl & 3) * 256;
        n0 = (tl >> 2) * 256;
        Ab = hT + (long)zb * HH * LL; Bb = Ab;
        K  = LL; kbase = zs * (LL / 4);
        Cb = P + (long)pl * HH * HH;
    }

    // prologue: tile0 fully + tile1's first 3 halves; drain tile0.
    E_STAGE_A(0, 0, 0); E_STAGE_B(0, 1, 0); E_STAGE_A(0, 1, 0);
    E_STAGE_B(0, 0, 0);
    E_STAGE_A(1, 0, 1); E_STAGE_B(1, 1, 1); E_STAGE_A(1, 1, 1);
    E_VM(6); E_BAR();
    int t_ = 0;
#pragma unroll 1
    for (; t_ + 3 < 16; t_ += 2) {
        /* P1 */ E_LOAD_A(0, 0); E_LOAD_Bv(0, 0, bfv0); E_STAGE_B(t_ + 1, 0, 1);
                 E_BAR(); E_LGKM0(); E_MMA(0, 0, bfv0); E_BAR();
        /* P2 */ E_LOAD_Bv(0, 1, bfv1); E_STAGE_A(t_ + 2, 0, 0);
                 E_BAR(); E_LGKM0(); E_MMA(0, 1, bfv1); E_BAR();
        /* P3 */ E_LOAD_A(0, 1); E_STAGE_B(t_ + 2, 1, 0);
                 E_BAR(); E_LGKM0(); E_MMA(1, 1, bfv1); E_BAR();
        /* P4 */ E_STAGE_A(t_ + 2, 1, 0);
                 E_MMA(1, 0, bfv0); E_VM(6); E_BAR();
        /* P5 */ E_LOAD_A(1, 0); E_LOAD_Bv(1, 0, bfv0); E_STAGE_B(t_ + 2, 0, 0);
                 E_BAR(); E_LGKM0(); E_MMA(0, 0, bfv0); E_BAR();
        /* P6 */ E_LOAD_Bv(1, 1, bfv1); E_STAGE_A(t_ + 3, 0, 1);
                 E_BAR(); E_LGKM0(); E_MMA(0, 1, bfv1); E_BAR();
        /* P7 */ E_LOAD_A(1, 1); E_STAGE_B(t_ + 3, 1, 1);
                 E_BAR(); E_LGKM0(); E_MMA(1, 1, bfv1); E_BAR();
        /* P8 */ E_STAGE_A(t_ + 3, 1, 1);
                 E_MMA(1, 0, bfv0); E_VM(6); E_BAR();
    }
    // epilogue pair: only B(NT-1)p0 left to stage
    E_LOAD_A(0, 0); E_LOAD_Bv(0, 0, bfv0); E_STAGE_B(t_ + 1, 0, 1);
    E_BAR(); E_LGKM0(); E_MMA(0, 0, bfv0); E_BAR();
    E_LOAD_Bv(0, 1, bfv1); E_BAR(); E_LGKM0(); E_MMA(0, 1, bfv1); E_BAR();
    E_LOAD_A(0, 1); E_BAR(); E_LGKM0(); E_MMA(1, 1, bfv1); E_BAR();
    E_MMA(1, 0, bfv0); E_VM(0); E_BAR();
    E_LOAD_A(1, 0); E_LOAD_Bv(1, 0, bfv0); E_BAR(); E_LGKM0(); E_MMA(0, 0, bfv0); E_BAR();
    E_LOAD_Bv(1, 1, bfv1); E_BAR(); E_LGKM0(); E_MMA(0, 1, bfv1); E_BAR();
    E_LOAD_A(1, 1); E_BAR(); E_LGKM0(); E_MMA(1, 1, bfv1); E_BAR();
    E_MMA(1, 0, bfv0);

    // C/D layout per 16x16 frag: col = lane&15 (fr), row = (lane>>4)*4 + reg.
#pragma unroll
    for (int gi = 0; gi < 8; ++gi)
#pragma unroll
        for (int r = 0; r < 4; ++r) {
            const int row = m0 + wr * 128 + gi * 16 + fq * 4 + r;
#pragma unroll
            for (int gj = 0; gj < 4; ++gj)
                Cb[(long)row * HH + n0 + wc * 64 + gj * 16 + fr] = (bf16)acc[gi][gj][r];
        }
}

// ---------------------------------------------------------------------------
// O_b = q_b · G_b^T (G symmetric -> exact). 8-phase BM=256 x BN=128 engine,
// 256 blocks x 512 threads, T1 remap. EXACT R3 schedule: vm(5) at P4/P8.
// ---------------------------------------------------------------------------
__global__ __launch_bounds__(512, 2) void gemm8_qG(
    const bf16* __restrict__ qm, const bf16* __restrict__ G, float* __restrict__ out)
{
    __shared__ __align__(16) bf16 As[2][2][128][64];
    __shared__ __align__(16) bf16 Bs2[2][2][64][64];
    E_COMMON_IDX();
    bf16x8 af[4][2], bw0[2], bw1[2];
    f32x4 acc2[8][2];
#pragma unroll
    for (int i_ = 0; i_ < 8; ++i_)
#pragma unroll
        for (int j_ = 0; j_ < 2; ++j_) acc2[i_][j_] = (f32x4){0.f, 0.f, 0.f, 0.f};

    const int bid = blockIdx.x;
    const int id  = (bid & 7) * 32 + (bid >> 3);   // XCD-chunked bijection
    const int mb  = id >> 3;              // 0..31: batch*16 + m-tile
    const int b   = mb >> 4;
    const int m0  = (mb & 15) * 256;
    const int n0  = (id & 7) * 128;
    const bf16* Ab = qm + (long)b * LL * HH;
    const bf16* Bb = G + (long)b * HH * HH;
    const int K = HH, kbase = 0;
    float* outb = out + (long)b * LL * HH;

    // prologue: tile0 fully + tile1's A halves + B p1; drain tile0 (vm(5)).
    E_STAGE_A(0, 0, 0); E_STAGE_B2(0, 1, 0); E_STAGE_A(0, 1, 0);
    E_STAGE_B2(0, 0, 0);
    E_STAGE_A(1, 0, 1); E_STAGE_B2(1, 1, 1); E_STAGE_A(1, 1, 1);
    E_VM(5); E_BAR();
    int t_ = 0;
#pragma unroll 1
    for (; t_ + 3 < 16; t_ += 2) {
        /* P1 */ E_LOAD_A(0, 0); E_LOAD_B2(0, 0, bw0); E_STAGE_B2(t_ + 1, 0, 1);
                 E_BAR(); E_LGKM0(); E_MMA2(0, 0, bw0); E_BAR();
        /* P2 */ E_LOAD_B2(0, 1, bw1); E_STAGE_A(t_ + 2, 0, 0);
                 E_BAR(); E_LGKM0(); E_MMA2(0, 1, bw1); E_BAR();
        /* P3 */ E_LOAD_A(0, 1); E_STAGE_B2(t_ + 2, 1, 0);
                 E_BAR(); E_LGKM0(); E_MMA2(1, 1, bw1); E_BAR();
        /* P4 */ E_STAGE_A(t_ + 2, 1, 0);
                 E_MMA2(1, 0, bw0); E_VM(5); E_BAR();
        /* P5 */ E_LOAD_A(1, 0); E_LOAD_B2(1, 0, bw0); E_STAGE_B2(t_ + 2, 0, 0);
                 E_BAR(); E_LGKM0(); E_MMA2(0, 0, bw0); E_BAR();
        /* P6 */ E_LOAD_B2(1, 1, bw1); E_STAGE_A(t_ + 3, 0, 1);
                 E_BAR(); E_LGKM0(); E_MMA2(0, 1, bw1); E_BAR();
        /* P7 */ E_LOAD_A(1, 1); E_STAGE_B2(t_ + 3, 1, 1);
                 E_BAR(); E_LGKM0(); E_MMA2(1, 1, bw1); E_BAR();
        /* P8 */ E_STAGE_A(t_ + 3, 1, 1);
                 E_MMA2(1, 0, bw0); E_VM(5); E_BAR();
    }
    // epilogue pair
    E_LOAD_A(0, 0); E_LOAD_B2(0, 0, bw0); E_STAGE_B2(t_ + 1, 0, 1);
    E_BAR(); E_LGKM0(); E_MMA2(0, 0, bw0); E_BAR();
    E_LOAD_B2(0, 1, bw1); E_BAR(); E_LGKM0(); E_MMA2(0, 1, bw1); E_BAR();
    E_LOAD_A(0, 1); E_BAR(); E_LGKM0(); E_MMA2(1, 1, bw1); E_BAR();
    E_MMA2(1, 0, bw0); E_VM(0); E_BAR();
    E_LOAD_A(1, 0); E_LOAD_B2(1, 0, bw0); E_BAR(); E_LGKM0(); E_MMA2(0, 0, bw0); E_BAR();
    E_LOAD_B2(1, 1, bw1); E_BAR(); E_LGKM0(); E_MMA2(0, 1, bw1); E_BAR();
    E_LOAD_A(1, 1); E_BAR(); E_LGKM0(); E_MMA2(1, 1, bw1); E_BAR();
    E_MMA2(1, 0, bw0);

#pragma unroll
    for (int gi = 0; gi < 8; ++gi)
#pragma unroll
        for (int r = 0; r < 4; ++r) {
            const int row = m0 + wr * 128 + gi * 16 + fq * 4 + r;
#pragma unroll
            for (int gj = 0; gj < 2; ++gj)
                outb[(long)row * HH + n0 + wc * 32 + gj * 16 + fr] = acc2[gi][gj][r];
        }
}

// sum S bf16 partial planes -> bf16 (fp32 accumulate). 8 elems/thread.
// grid (npb/2048, B), block 256.
__global__ __launch_bounds__(256) void reduce_splits(
    const bf16* __restrict__ P, bf16* __restrict__ out, const int npb, const int S)
{
    const int b = blockIdx.y;
    const long r = ((long)blockIdx.x * 256 + threadIdx.x) * 8;
    const bf16* base = P + (long)b * S * npb + r;
    float a[8];
    {
        const bf16x8 v = *(const bf16x8*)(base);
#pragma unroll
        for (int j = 0; j < 8; ++j) a[j] = (float)v[j];
    }
    for (int s = 1; s < S; ++s) {
        const bf16x8 v = *(const bf16x8*)(base + (long)s * npb);
#pragma unroll
        for (int j = 0; j < 8; ++j) a[j] += (float)v[j];
    }
    bf16x8 o;
#pragma unroll
    for (int j = 0; j < 8; ++j) o[j] = (bf16)a[j];
    *(bf16x8*)(out + (long)b * npb + r) = o;
}

// ---------------------------------------------------------------------------
// Pipeline (4 dispatches): prep (batch-paired, -16MB table re-read);
//   merged 8-phase Gq (bf16 partials); reduce; qG.
// Workspace: h@0 (16M) | hT@16M | Wb@32M | G@34M | P@38M (16M bf16) | q@70M
// ---------------------------------------------------------------------------
extern "C" void kernel_launch(void* const* d_in, const int* in_sizes, int n_in,
                              void* d_out, int out_size, void* d_ws, size_t ws_size,
                              hipStream_t stream)
{
    const float* x  = (const float*)d_in[0];   // hidden_states [B,L,H]
    const float* Wq = (const float*)d_in[1];   // [H,H]
    const float* cs = (const float*)d_in[2];   // [L,H]
    const float* sn = (const float*)d_in[3];   // [L,H]
    float* out = (float*)d_out;                // [B,L,H] fp32
    char* ws = (char*)d_ws;

    bf16*  h  = (bf16*)(ws);
    bf16*  hT = (bf16*)(ws + 16u * 1024 * 1024);
    bf16*  Wb = (bf16*)(ws + 32u * 1024 * 1024);
    bf16*  G  = (bf16*)(ws + 34u * 1024 * 1024);
    bf16*  P  = (bf16*)(ws + 38u * 1024 * 1024);   // 8 planes of H*H bf16

    const bool big_ws = ws_size >= (size_t)90 * 1024 * 1024;
    bf16* q = big_ws ? (bf16*)(ws + 70u * 1024 * 1024)
                     : (bf16*)(ws + 54u * 1024 * 1024);  // fallback: after P

    if (big_ws) {
        // 1) fused RoPE + transpose + Wq cast (512 batch-paired tile blocks
        //    + 256 cast blocks)
        prep_kernel<<<dim3(768), 256, 0, stream>>>(x, cs, sn, Wq, h, hT, Wb);
        // 2) merged 8-phase: G split-K partials (bf16) + q GEMM, 256 blocks
        gemm8_Gq<<<dim3(256), 512, 0, stream>>>(hT, Wb, h, P, q);
        // 3) G = sum of 4 planes per batch
        reduce_splits<<<dim3(HH * HH / 2048, BB), 256, 0, stream>>>(P, G, HH * HH, 4);
        // 4) O_b = q_b @ G_b, 8-phase 256-block engine
        gemm8_qG<<<dim3(256), 512, 0, stream>>>(q, G, out);
    } else {
        rope_kernel<<<dim3(LL, BB), 128, 0, stream>>>(x, cs, sn, h);
        transpose_bf16_64<<<dim3(LL / 64, HH / 64, BB), 256, 0, stream>>>(h, hT, LL, HH);
        cast_wq<<<dim3(HH * HH / 1024), 256, 0, stream>>>(Wq, Wb);
        gemm_bt<bf16><<<dim3(HH / 128, HH / 128, BB), 256, 0, stream>>>(
            hT, hT, G, HH, HH, LL, (long)HH * LL, (long)HH * LL, (long)HH * HH);
        gemm_bt<bf16><<<dim3(LL / 128, HH / 128, BB), 256, 0, stream>>>(
            h, Wb, q, LL, HH, HH, (long)LL * HH, 0L, (long)LL * HH);
        gemm_bt<float><<<dim3(LL / 128, HH / 128, BB), 256, 0, stream>>>(
            q, G, out, LL, HH, HH, (long)LL * HH, (long)HH * HH, (long)LL * HH);
    }
}